// Round 1
// baseline (967.418 us; speedup 1.0000x reference)
//
#include <hip/hip_runtime.h>
#include <math.h>

constexpr int NN  = 100000;   // nodes
constexpr int NE  = 1600000;  // edges
constexpr int DIM = 128;

// ---- workspace layout (bytes, 512-aligned) ----
constexpr size_t OFF_FLAG   = 0;
constexpr size_t OFF_ROWPTR = 512;                       // int[NN+1]
constexpr size_t OFF_WCUR   = OFF_ROWPTR + 400128;       // int[NN]
constexpr size_t OFF_COL    = OFF_WCUR   + 400128;       // int[NE]
constexpr size_t OFF_M      = OFF_COL    + 6400000;      // float[NN*DIM]
constexpr size_t OFF_H      = OFF_M      + 51200000;     // float[NN*DIM]
// total ≈ 109.6 MB

__device__ __forceinline__ int eidx(const void* p, int is64, long long i) {
  return is64 ? (int)((const long long*)p)[i] : ((const int*)p)[i];
}

// Detect int64 vs int32 edge_index: sample odd 32-bit words of the src row.
// int64 little-endian with values < 2^31 -> high words all zero.
__global__ void k_detect(const unsigned int* e, int* flag) {
  unsigned int v = 0;
  for (int i = threadIdx.x; i < 8192; i += blockDim.x) v |= e[2 * i + 1];
  if (v) atomicOr(flag, 1);   // nonzero high word found -> int32
}

__global__ void k_hist(const void* e, const int* flag, int* rowptr) {
  int is64 = (*flag == 0);
  int i = blockIdx.x * blockDim.x + threadIdx.x;
  if (i < NE) {
    int dst = eidx(e, is64, (long long)NE + i);
    atomicAdd(&rowptr[dst + 1], 1);
  }
}

// Single-block inclusive scan over rowptr[0..NN]; also seeds wcur.
__global__ void k_scan(int* rowptr, int* wcur) {
  const int n = NN + 1;
  const int CH = (n + 1023) / 1024;  // 98
  __shared__ int part[1024];
  int t = threadIdx.x;
  int base = t * CH;
  int s = 0;
  for (int i = 0; i < CH; i++) {
    int idx = base + i;
    if (idx < n) s += rowptr[idx];
  }
  part[t] = s;
  __syncthreads();
  for (int off = 1; off < 1024; off <<= 1) {
    int v = (t >= off) ? part[t - off] : 0;
    __syncthreads();
    part[t] += v;
    __syncthreads();
  }
  int run = (t == 0) ? 0 : part[t - 1];
  for (int i = 0; i < CH; i++) {
    int idx = base + i;
    if (idx < n) {
      run += rowptr[idx];
      rowptr[idx] = run;
      if (idx < NN) wcur[idx] = run;
    }
  }
}

__global__ void k_scatter(const void* e, const int* flag, int* wcur, int* col) {
  int is64 = (*flag == 0);
  int i = blockIdx.x * blockDim.x + threadIdx.x;
  if (i < NE) {
    int src = eidx(e, is64, i);
    int dst = eidx(e, is64, (long long)NE + i);
    int p = atomicAdd(&wcur[dst], 1);
    col[p] = src;
  }
}

// One wave (64 lanes) per node: mean over in-edges, float2 per lane.
__global__ void k_agg(const float* __restrict__ feat,
                      const int* __restrict__ rowptr,
                      const int* __restrict__ col,
                      float* __restrict__ out) {
  int gtid = blockIdx.x * blockDim.x + threadIdx.x;
  int v = gtid >> 6;
  int lane = gtid & 63;
  if (v >= NN) return;
  int beg = rowptr[v], end = rowptr[v + 1];
  float2 acc = {0.f, 0.f};
  for (int j = beg; j < end; j++) {
    int c = col[j];
    float2 t = ((const float2*)(feat + (size_t)c * DIM))[lane];
    acc.x += t.x;
    acc.y += t.y;
  }
  float inv = 1.0f / (float)max(end - beg, 1);
  acc.x *= inv;
  acc.y *= inv;
  ((float2*)(out + (size_t)v * DIM))[lane] = acc;
}

// C = relu(A1@B1 + A2@B2 + bias); MODE 0: store [NN,DIM]; MODE 1: fused heads.
// Block 256 threads = 64 rows x 128 cols tile; thread = 8 rows x 4 cols.
template <int MODE>
__global__ __launch_bounds__(256) void k_gemm(
    const float* __restrict__ A1, const float* __restrict__ A2,
    const float* __restrict__ B1, const float* __restrict__ B2,
    const float* __restrict__ bias, float* __restrict__ out,
    const float* __restrict__ Wp, const float* __restrict__ bp,
    const float* __restrict__ Wd, const float* __restrict__ bd) {
  __shared__ float As[32][64];    // k-major A tile
  __shared__ float Bs[32][128];
  int tid = threadIdx.x;
  int tx = tid & 31, ty = tid >> 5;
  int block_row = blockIdx.x * 64;
  float acc[8][4];
#pragma unroll
  for (int i = 0; i < 8; i++)
#pragma unroll
    for (int j = 0; j < 4; j++) acc[i][j] = 0.f;

  for (int kb = 0; kb < 256; kb += 32) {
    const float* A = (kb < 128) ? A1 : A2;
    const float* B = (kb < 128) ? B1 : B2;
    int kOff = kb & 127;
    // stage A: 64 rows x 32 k (transposed into LDS)
    {
      int r = tid & 63;
      int c = tid >> 6;  // 0..3
#pragma unroll
      for (int rep = 0; rep < 2; rep++) {
        int k4 = c + rep * 4;  // 0..7
        int row = block_row + r;
        float4 v = {0.f, 0.f, 0.f, 0.f};
        if (row < NN) v = *(const float4*)(A + (size_t)row * DIM + kOff + k4 * 4);
        int k0 = k4 * 4;
        As[k0 + 0][r] = v.x;
        As[k0 + 1][r] = v.y;
        As[k0 + 2][r] = v.z;
        As[k0 + 3][r] = v.w;
      }
    }
    // stage B: 32 k x 128 cols
#pragma unroll
    for (int rep = 0; rep < 4; rep++) {
      int kk = ty + rep * 8;  // 0..31
      float4 v = *(const float4*)(B + (size_t)(kOff + kk) * DIM + tx * 4);
      *(float4*)&Bs[kk][tx * 4] = v;
    }
    __syncthreads();
#pragma unroll
    for (int k = 0; k < 32; k++) {
      float4 a0 = *(const float4*)&As[k][ty * 8];
      float4 a1 = *(const float4*)&As[k][ty * 8 + 4];
      float4 b = *(const float4*)&Bs[k][tx * 4];
      float av[8] = {a0.x, a0.y, a0.z, a0.w, a1.x, a1.y, a1.z, a1.w};
      float bv[4] = {b.x, b.y, b.z, b.w};
#pragma unroll
      for (int i = 0; i < 8; i++)
#pragma unroll
        for (int j = 0; j < 4; j++) acc[i][j] += av[i] * bv[j];
    }
    __syncthreads();
  }

  const float4 bb = *(const float4*)(bias + tx * 4);
  if (MODE == 0) {
#pragma unroll
    for (int i = 0; i < 8; i++) {
      int r = block_row + ty * 8 + i;
      if (r < NN) {
        float4 o;
        o.x = fmaxf(acc[i][0] + bb.x, 0.f);
        o.y = fmaxf(acc[i][1] + bb.y, 0.f);
        o.z = fmaxf(acc[i][2] + bb.z, 0.f);
        o.w = fmaxf(acc[i][3] + bb.w, 0.f);
        *(float4*)(out + (size_t)r * DIM + tx * 4) = o;
      }
    }
  } else {
    const float4 wp = *(const float4*)(Wp + tx * 4);
    const float4 wd = *(const float4*)(Wd + tx * 4);
    float bpv = bp[0], bdv = bd[0];
#pragma unroll
    for (int i = 0; i < 8; i++) {
      int r = block_row + ty * 8 + i;
      float h0 = fmaxf(acc[i][0] + bb.x, 0.f);
      float h1 = fmaxf(acc[i][1] + bb.y, 0.f);
      float h2 = fmaxf(acc[i][2] + bb.z, 0.f);
      float h3 = fmaxf(acc[i][3] + bb.w, 0.f);
      float p = h0 * wp.x + h1 * wp.y + h2 * wp.z + h3 * wp.w;
      float dv = h0 * wd.x + h1 * wd.y + h2 * wd.z + h3 * wd.w;
#pragma unroll
      for (int m = 16; m >= 1; m >>= 1) {
        p += __shfl_xor(p, m, 32);
        dv += __shfl_xor(dv, m, 32);
      }
      if (tx == 0 && r < NN) {
        float preds = p + bpv;
        float diffs = 1.f / (1.f + expf(-(dv + bdv)));
        out[r] = preds - diffs;
        out[NN + r] = preds + diffs;
      }
    }
  }
}

extern "C" void kernel_launch(void* const* d_in, const int* in_sizes, int n_in,
                              void* d_out, int out_size, void* d_ws, size_t ws_size,
                              hipStream_t stream) {
  const float* x   = (const float*)d_in[0];
  const void*  ei  = d_in[1];
  const float* W1l = (const float*)d_in[2];
  const float* b1  = (const float*)d_in[3];
  const float* W1r = (const float*)d_in[4];
  const float* W2l = (const float*)d_in[5];
  const float* b2  = (const float*)d_in[6];
  const float* W2r = (const float*)d_in[7];
  const float* Wp  = (const float*)d_in[8];
  const float* bp  = (const float*)d_in[9];
  const float* Wd  = (const float*)d_in[10];
  const float* bd  = (const float*)d_in[11];
  float* out = (float*)d_out;

  char* ws = (char*)d_ws;
  int* flag     = (int*)(ws + OFF_FLAG);
  int* rowptr   = (int*)(ws + OFF_ROWPTR);
  int* wcur     = (int*)(ws + OFF_WCUR);
  int* col      = (int*)(ws + OFF_COL);
  float* M      = (float*)(ws + OFF_M);
  float* H      = (float*)(ws + OFF_H);

  hipMemsetAsync(flag, 0, sizeof(int), stream);
  hipMemsetAsync(rowptr, 0, (NN + 1) * sizeof(int), stream);
  k_detect<<<1, 256, 0, stream>>>((const unsigned int*)ei, flag);
  k_hist<<<(NE + 255) / 256, 256, 0, stream>>>(ei, flag, rowptr);
  k_scan<<<1, 1024, 0, stream>>>(rowptr, wcur);
  k_scatter<<<(NE + 255) / 256, 256, 0, stream>>>(ei, flag, wcur, col);

  // layer 1
  k_agg<<<(NN * 64 + 255) / 256, 256, 0, stream>>>(x, rowptr, col, M);
  k_gemm<0><<<(NN + 63) / 64, 256, 0, stream>>>(M, x, W1l, W1r, b1, H,
                                                nullptr, nullptr, nullptr, nullptr);
  // layer 2 + heads
  k_agg<<<(NN * 64 + 255) / 256, 256, 0, stream>>>(H, rowptr, col, M);
  k_gemm<1><<<(NN + 63) / 64, 256, 0, stream>>>(M, H, W2l, W2r, b2, out,
                                                Wp, bp, Wd, bd);
}

// Round 2
// 723.037 us; speedup vs baseline: 1.3380x; 1.3380x over previous
//
#include <hip/hip_runtime.h>
#include <math.h>

constexpr int NN  = 100000;   // nodes
constexpr int NE  = 1600000;  // edges
constexpr int DIM = 128;
constexpr int NB  = (NN + 1 + 1023) / 1024;  // 98 scan blocks

// ---- workspace layout (bytes, 512-aligned) ----
constexpr size_t OFF_FLAG   = 0;
constexpr size_t OFF_BSUM   = 512;                       // int[NB] (+pad)
constexpr size_t OFF_ROWPTR = 1536;                      // int[NN+1]
constexpr size_t OFF_WCUR   = OFF_ROWPTR + 400128;       // int[NN]
constexpr size_t OFF_COL    = OFF_WCUR   + 400128;       // int[NE]
constexpr size_t OFF_M      = OFF_COL    + 6400000;      // float[NN*DIM]
constexpr size_t OFF_H      = OFF_M      + 51200000;     // float[NN*DIM]
// total ≈ 109.6 MB

__device__ __forceinline__ int eidx(const void* p, int is64, long long i) {
  return is64 ? (int)((const long long*)p)[i] : ((const int*)p)[i];
}

// Detect int64 vs int32 edge_index: sample odd 32-bit words of the src row.
__global__ void k_detect(const unsigned int* e, int* flag) {
  unsigned int v = 0;
  for (int i = threadIdx.x; i < 8192; i += blockDim.x) v |= e[2 * i + 1];
  if (v) atomicOr(flag, 1);   // nonzero high word found -> int32
}

__global__ void k_hist(const void* e, const int* flag, int* rowptr) {
  int is64 = (*flag == 0);
  int i = blockIdx.x * blockDim.x + threadIdx.x;
  if (i < NE) {
    int dst = eidx(e, is64, (long long)NE + i);
    atomicAdd(&rowptr[dst + 1], 1);
  }
}

// ---- hierarchical scan: a) per-block inclusive scan, b) scan block sums,
//      c) add offsets + seed wcur ----
__global__ __launch_bounds__(1024) void k_scan_a(int* rowptr, int* bsum) {
  int gid = blockIdx.x * 1024 + threadIdx.x;
  int lane = threadIdx.x & 63;
  int wid = threadIdx.x >> 6;  // 0..15
  int s = (gid < NN + 1) ? rowptr[gid] : 0;
#pragma unroll
  for (int off = 1; off < 64; off <<= 1) {
    int t = __shfl_up(s, off, 64);
    if (lane >= off) s += t;
  }
  __shared__ int wsum[16];
  if (lane == 63) wsum[wid] = s;
  __syncthreads();
  if (wid == 0) {
    int ws = (lane < 16) ? wsum[lane] : 0;
#pragma unroll
    for (int off = 1; off < 16; off <<= 1) {
      int t = __shfl_up(ws, off, 64);
      if (lane >= off) ws += t;
    }
    if (lane < 16) wsum[lane] = ws;
  }
  __syncthreads();
  if (wid > 0) s += wsum[wid - 1];
  if (gid < NN + 1) rowptr[gid] = s;
  if (threadIdx.x == 1023) bsum[blockIdx.x] = s;  // block total
}

__global__ void k_scan_b(int* bsum) {
  __shared__ int sh[128];
  int t = threadIdx.x;  // 128 threads
  sh[t] = (t < NB) ? bsum[t] : 0;
  __syncthreads();
  for (int off = 1; off < 128; off <<= 1) {
    int v = (t >= off) ? sh[t - off] : 0;
    __syncthreads();
    sh[t] += v;
    __syncthreads();
  }
  if (t < NB) bsum[t] = (t > 0) ? sh[t - 1] : 0;  // exclusive
}

__global__ __launch_bounds__(1024) void k_scan_c(int* rowptr, const int* bsum,
                                                 int* wcur) {
  int gid = blockIdx.x * 1024 + threadIdx.x;
  if (gid < NN + 1) {
    int v = rowptr[gid] + bsum[blockIdx.x];
    rowptr[gid] = v;
    if (gid < NN) wcur[gid] = v;
  }
}

__global__ void k_scatter(const void* e, const int* flag, int* wcur, int* col) {
  int is64 = (*flag == 0);
  int i = blockIdx.x * blockDim.x + threadIdx.x;
  if (i < NE) {
    int src = eidx(e, is64, i);
    int dst = eidx(e, is64, (long long)NE + i);
    int p = atomicAdd(&wcur[dst], 1);
    col[p] = src;
  }
}

// One wave (64 lanes) per node: mean over in-edges, float2 per lane.
__global__ void k_agg(const float* __restrict__ feat,
                      const int* __restrict__ rowptr,
                      const int* __restrict__ col,
                      float* __restrict__ out) {
  int gtid = blockIdx.x * blockDim.x + threadIdx.x;
  int v = gtid >> 6;
  int lane = gtid & 63;
  if (v >= NN) return;
  int beg = rowptr[v], end = rowptr[v + 1];
  float2 acc = {0.f, 0.f};
  for (int j = beg; j < end; j++) {
    int c = col[j];
    float2 t = ((const float2*)(feat + (size_t)c * DIM))[lane];
    acc.x += t.x;
    acc.y += t.y;
  }
  float inv = 1.0f / (float)max(end - beg, 1);
  acc.x *= inv;
  acc.y *= inv;
  ((float2*)(out + (size_t)v * DIM))[lane] = acc;
}

// C = relu(A1@B1 + A2@B2 + bias); MODE 0: store [NN,DIM]; MODE 1: fused heads.
// Block 256 threads = 64 rows x 128 cols tile; thread = 8 rows x 4 cols.
template <int MODE>
__global__ __launch_bounds__(256) void k_gemm(
    const float* __restrict__ A1, const float* __restrict__ A2,
    const float* __restrict__ B1, const float* __restrict__ B2,
    const float* __restrict__ bias, float* __restrict__ out,
    const float* __restrict__ Wp, const float* __restrict__ bp,
    const float* __restrict__ Wd, const float* __restrict__ bd) {
  __shared__ float As[32][64];    // k-major A tile
  __shared__ float Bs[32][128];
  int tid = threadIdx.x;
  int tx = tid & 31, ty = tid >> 5;
  int block_row = blockIdx.x * 64;
  float acc[8][4];
#pragma unroll
  for (int i = 0; i < 8; i++)
#pragma unroll
    for (int j = 0; j < 4; j++) acc[i][j] = 0.f;

  for (int kb = 0; kb < 256; kb += 32) {
    const float* A = (kb < 128) ? A1 : A2;
    const float* B = (kb < 128) ? B1 : B2;
    int kOff = kb & 127;
    // stage A: 64 rows x 32 k (transposed into LDS)
    {
      int r = tid & 63;
      int c = tid >> 6;  // 0..3
#pragma unroll
      for (int rep = 0; rep < 2; rep++) {
        int k4 = c + rep * 4;  // 0..7
        int row = block_row + r;
        float4 v = {0.f, 0.f, 0.f, 0.f};
        if (row < NN) v = *(const float4*)(A + (size_t)row * DIM + kOff + k4 * 4);
        int k0 = k4 * 4;
        As[k0 + 0][r] = v.x;
        As[k0 + 1][r] = v.y;
        As[k0 + 2][r] = v.z;
        As[k0 + 3][r] = v.w;
      }
    }
    // stage B: 32 k x 128 cols
#pragma unroll
    for (int rep = 0; rep < 4; rep++) {
      int kk = ty + rep * 8;  // 0..31
      float4 v = *(const float4*)(B + (size_t)(kOff + kk) * DIM + tx * 4);
      *(float4*)&Bs[kk][tx * 4] = v;
    }
    __syncthreads();
#pragma unroll
    for (int k = 0; k < 32; k++) {
      float4 a0 = *(const float4*)&As[k][ty * 8];
      float4 a1 = *(const float4*)&As[k][ty * 8 + 4];
      float4 b = *(const float4*)&Bs[k][tx * 4];
      float av[8] = {a0.x, a0.y, a0.z, a0.w, a1.x, a1.y, a1.z, a1.w};
      float bv[4] = {b.x, b.y, b.z, b.w};
#pragma unroll
      for (int i = 0; i < 8; i++)
#pragma unroll
        for (int j = 0; j < 4; j++) acc[i][j] += av[i] * bv[j];
    }
    __syncthreads();
  }

  const float4 bb = *(const float4*)(bias + tx * 4);
  if (MODE == 0) {
#pragma unroll
    for (int i = 0; i < 8; i++) {
      int r = block_row + ty * 8 + i;
      if (r < NN) {
        float4 o;
        o.x = fmaxf(acc[i][0] + bb.x, 0.f);
        o.y = fmaxf(acc[i][1] + bb.y, 0.f);
        o.z = fmaxf(acc[i][2] + bb.z, 0.f);
        o.w = fmaxf(acc[i][3] + bb.w, 0.f);
        *(float4*)(out + (size_t)r * DIM + tx * 4) = o;
      }
    }
  } else {
    const float4 wp = *(const float4*)(Wp + tx * 4);
    const float4 wd = *(const float4*)(Wd + tx * 4);
    float bpv = bp[0], bdv = bd[0];
#pragma unroll
    for (int i = 0; i < 8; i++) {
      int r = block_row + ty * 8 + i;
      float h0 = fmaxf(acc[i][0] + bb.x, 0.f);
      float h1 = fmaxf(acc[i][1] + bb.y, 0.f);
      float h2 = fmaxf(acc[i][2] + bb.z, 0.f);
      float h3 = fmaxf(acc[i][3] + bb.w, 0.f);
      float p = h0 * wp.x + h1 * wp.y + h2 * wp.z + h3 * wp.w;
      float dv = h0 * wd.x + h1 * wd.y + h2 * wd.z + h3 * wd.w;
#pragma unroll
      for (int m = 16; m >= 1; m >>= 1) {
        p += __shfl_xor(p, m, 32);
        dv += __shfl_xor(dv, m, 32);
      }
      if (tx == 0 && r < NN) {
        float preds = p + bpv;
        float diffs = 1.f / (1.f + expf(-(dv + bdv)));
        out[r] = preds - diffs;
        out[NN + r] = preds + diffs;
      }
    }
  }
}

extern "C" void kernel_launch(void* const* d_in, const int* in_sizes, int n_in,
                              void* d_out, int out_size, void* d_ws, size_t ws_size,
                              hipStream_t stream) {
  const float* x   = (const float*)d_in[0];
  const void*  ei  = d_in[1];
  const float* W1l = (const float*)d_in[2];
  const float* b1  = (const float*)d_in[3];
  const float* W1r = (const float*)d_in[4];
  const float* W2l = (const float*)d_in[5];
  const float* b2  = (const float*)d_in[6];
  const float* W2r = (const float*)d_in[7];
  const float* Wp  = (const float*)d_in[8];
  const float* bp  = (const float*)d_in[9];
  const float* Wd  = (const float*)d_in[10];
  const float* bd  = (const float*)d_in[11];
  float* out = (float*)d_out;

  char* ws = (char*)d_ws;
  int* flag     = (int*)(ws + OFF_FLAG);
  int* bsum     = (int*)(ws + OFF_BSUM);
  int* rowptr   = (int*)(ws + OFF_ROWPTR);
  int* wcur     = (int*)(ws + OFF_WCUR);
  int* col      = (int*)(ws + OFF_COL);
  float* M      = (float*)(ws + OFF_M);
  float* H      = (float*)(ws + OFF_H);

  hipMemsetAsync(flag, 0, sizeof(int), stream);
  hipMemsetAsync(rowptr, 0, (NN + 1) * sizeof(int), stream);
  k_detect<<<1, 256, 0, stream>>>((const unsigned int*)ei, flag);
  k_hist<<<(NE + 255) / 256, 256, 0, stream>>>(ei, flag, rowptr);
  k_scan_a<<<NB, 1024, 0, stream>>>(rowptr, bsum);
  k_scan_b<<<1, 128, 0, stream>>>(bsum);
  k_scan_c<<<NB, 1024, 0, stream>>>(rowptr, bsum, wcur);
  k_scatter<<<(NE + 255) / 256, 256, 0, stream>>>(ei, flag, wcur, col);

  // layer 1
  k_agg<<<(NN * 64 + 255) / 256, 256, 0, stream>>>(x, rowptr, col, M);
  k_gemm<0><<<(NN + 63) / 64, 256, 0, stream>>>(M, x, W1l, W1r, b1, H,
                                                nullptr, nullptr, nullptr, nullptr);
  // layer 2 + heads
  k_agg<<<(NN * 64 + 255) / 256, 256, 0, stream>>>(H, rowptr, col, M);
  k_gemm<1><<<(NN + 63) / 64, 256, 0, stream>>>(M, H, W2l, W2r, b2, out,
                                                Wp, bp, Wd, bd);
}

// Round 3
// 543.346 us; speedup vs baseline: 1.7805x; 1.3307x over previous
//
#include <hip/hip_runtime.h>
#include <math.h>

constexpr int NN  = 100000;   // nodes
constexpr int NE  = 1600000;  // edges
constexpr int DIM = 128;
constexpr int NB  = (NN + 1 + 1023) / 1024;  // 98 scan blocks

typedef unsigned short ushort;
typedef unsigned int uint;
typedef __attribute__((ext_vector_type(8))) short bf16x8;
typedef __attribute__((ext_vector_type(4))) float f32x4;

// ---- workspace layout (bytes) ----
constexpr size_t OFF_FLAG   = 0;
constexpr size_t OFF_BSUM   = 512;
constexpr size_t OFF_ROWPTR = 1536;                      // int[NN+1]
constexpr size_t OFF_WCUR   = OFF_ROWPTR + 400128;       // int[NN]
constexpr size_t OFF_COL    = OFF_WCUR   + 400128;       // int[NE]
constexpr size_t OFF_WT     = OFF_COL    + 6400000;      // 4 x 128x128 bf16 (transposed)
constexpr size_t OFF_XB     = OFF_WT     + 131072;       // bf16[NN*128]
constexpr size_t OFF_HB     = OFF_XB     + 25600000;     // bf16[NN*128]
constexpr size_t OFF_MB     = OFF_HB     + 25600000;     // bf16[NN*128]
// total ≈ 84.1 MB

__device__ __forceinline__ int eidx(const void* p, int is64, long long i) {
  return is64 ? (int)((const long long*)p)[i] : ((const int*)p)[i];
}

__device__ __forceinline__ ushort f2b(float f) {  // fp32 -> bf16 RNE
  uint u = __float_as_uint(f);
  return (ushort)((u + 0x7FFFu + ((u >> 16) & 1u)) >> 16);
}
__device__ __forceinline__ float blo(uint u) { return __uint_as_float(u << 16); }
__device__ __forceinline__ float bhi(uint u) { return __uint_as_float(u & 0xFFFF0000u); }

// Detect int64 vs int32 edge_index.
__global__ void k_detect(const uint* e, int* flag) {
  uint v = 0;
  for (int i = threadIdx.x; i < 8192; i += blockDim.x) v |= e[2 * i + 1];
  if (v) atomicOr(flag, 1);
}

__global__ void k_hist(const void* e, const int* flag, int* rowptr) {
  int is64 = (*flag == 0);
  int i = blockIdx.x * blockDim.x + threadIdx.x;
  if (i < NE) {
    int dst = eidx(e, is64, (long long)NE + i);
    atomicAdd(&rowptr[dst + 1], 1);
  }
}

// hierarchical scan
__global__ __launch_bounds__(1024) void k_scan_a(int* rowptr, int* bsum) {
  int gid = blockIdx.x * 1024 + threadIdx.x;
  int lane = threadIdx.x & 63;
  int wid = threadIdx.x >> 6;
  int s = (gid < NN + 1) ? rowptr[gid] : 0;
#pragma unroll
  for (int off = 1; off < 64; off <<= 1) {
    int t = __shfl_up(s, off, 64);
    if (lane >= off) s += t;
  }
  __shared__ int wsum[16];
  if (lane == 63) wsum[wid] = s;
  __syncthreads();
  if (wid == 0) {
    int ws = (lane < 16) ? wsum[lane] : 0;
#pragma unroll
    for (int off = 1; off < 16; off <<= 1) {
      int t = __shfl_up(ws, off, 64);
      if (lane >= off) ws += t;
    }
    if (lane < 16) wsum[lane] = ws;
  }
  __syncthreads();
  if (wid > 0) s += wsum[wid - 1];
  if (gid < NN + 1) rowptr[gid] = s;
  if (threadIdx.x == 1023) bsum[blockIdx.x] = s;
}

__global__ void k_scan_b(int* bsum) {
  __shared__ int sh[128];
  int t = threadIdx.x;
  sh[t] = (t < NB) ? bsum[t] : 0;
  __syncthreads();
  for (int off = 1; off < 128; off <<= 1) {
    int v = (t >= off) ? sh[t - off] : 0;
    __syncthreads();
    sh[t] += v;
    __syncthreads();
  }
  if (t < NB) bsum[t] = (t > 0) ? sh[t - 1] : 0;
}

__global__ __launch_bounds__(1024) void k_scan_c(int* rowptr, const int* bsum,
                                                 int* wcur) {
  int gid = blockIdx.x * 1024 + threadIdx.x;
  if (gid < NN + 1) {
    int v = rowptr[gid] + bsum[blockIdx.x];
    rowptr[gid] = v;
    if (gid < NN) wcur[gid] = v;
  }
}

__global__ void k_scatter(const void* e, const int* flag, int* wcur, int* col) {
  int is64 = (*flag == 0);
  int i = blockIdx.x * blockDim.x + threadIdx.x;
  if (i < NE) {
    int src = eidx(e, is64, i);
    int dst = eidx(e, is64, (long long)NE + i);
    int p = atomicAdd(&wcur[dst], 1);
    col[p] = src;
  }
}

// x fp32 -> bf16
__global__ void k_cvt(const float* __restrict__ x, ushort* __restrict__ xb) {
  int i = blockIdx.x * blockDim.x + threadIdx.x;  // one float4 each
  if (i * 4 < NN * DIM) {
    float4 v = ((const float4*)x)[i];
    ushort4 o = {f2b(v.x), f2b(v.y), f2b(v.z), f2b(v.w)};
    ((ushort4*)xb)[i] = o;
  }
}

// 4 weight matrices [k][n] fp32 -> transposed [n][k] bf16
__global__ void k_cvtw(const float* __restrict__ W1l, const float* __restrict__ W1r,
                       const float* __restrict__ W2l, const float* __restrict__ W2r,
                       ushort* __restrict__ WT) {
  int id = blockIdx.x * 256 + threadIdx.x;  // 65536 total
  int m = id >> 14, idx = id & 16383;
  int k = idx >> 7, n = idx & 127;
  const float* W = (m == 0) ? W1l : (m == 1) ? W1r : (m == 2) ? W2l : W2r;
  WT[m * 16384 + n * 128 + k] = f2b(W[k * 128 + n]);
}

// One wave per node: mean over in-edges of bf16 features, write bf16 mean.
__global__ void k_agg(const ushort* __restrict__ feat,
                      const int* __restrict__ rowptr,
                      const int* __restrict__ col,
                      ushort* __restrict__ out) {
  int gtid = blockIdx.x * blockDim.x + threadIdx.x;
  int v = gtid >> 6;
  int lane = gtid & 63;
  if (v >= NN) return;
  int beg = rowptr[v], end = rowptr[v + 1];
  const uint* F = (const uint*)feat;
  float ax = 0.f, ay = 0.f;
  int j = beg;
  for (; j + 1 < end; j += 2) {
    uint u0 = F[(size_t)col[j] * 64 + lane];
    uint u1 = F[(size_t)col[j + 1] * 64 + lane];
    ax += blo(u0) + blo(u1);
    ay += bhi(u0) + bhi(u1);
  }
  if (j < end) {
    uint u = F[(size_t)col[j] * 64 + lane];
    ax += blo(u);
    ay += bhi(u);
  }
  float inv = 1.0f / (float)max(end - beg, 1);
  ax *= inv;
  ay *= inv;
  ((uint*)out)[(size_t)v * 64 + lane] = (uint)f2b(ax) | ((uint)f2b(ay) << 16);
}

// MFMA GEMM: C = act(A1@W1 + A2@W2 + bias). A row-major bf16 [NN][128];
// B given transposed [n][k] bf16. Block=256 (4 waves), wave = 16 rows x 128 cols.
// MODE 0: relu -> bf16 out [NN][128]. MODE 1: relu -> heads -> d_out (2*NN fp32).
template <int MODE>
__global__ __launch_bounds__(256) void k_mm(
    const ushort* __restrict__ A1, const ushort* __restrict__ A2,
    const ushort* __restrict__ B1t, const ushort* __restrict__ B2t,
    const float* __restrict__ bias, void* __restrict__ outp,
    const float* __restrict__ Wp, const float* __restrict__ bp,
    const float* __restrict__ Wd, const float* __restrict__ bd) {
  int wid = threadIdx.x >> 6, lane = threadIdx.x & 63;
  int row0 = blockIdx.x * 64 + wid * 16;
  int r = lane & 15, kg = lane >> 4;  // fragment row/col index, k-group

  f32x4 acc[8];
#pragma unroll
  for (int f = 0; f < 8; f++) acc[f] = (f32x4){0.f, 0.f, 0.f, 0.f};

  int arow = row0 + r;
  bool aok = arow < NN;
  const ushort* Ar1 = A1 + (size_t)arow * DIM + kg * 8;
  const ushort* Ar2 = A2 + (size_t)arow * DIM + kg * 8;

#pragma unroll
  for (int half = 0; half < 2; half++) {
    const ushort* Ar = half ? Ar2 : Ar1;
    const ushort* Bt = half ? B2t : B1t;
#pragma unroll
    for (int ks = 0; ks < 4; ks++) {
      bf16x8 a = aok ? *(const bf16x8*)(Ar + ks * 32)
                     : (bf16x8){0, 0, 0, 0, 0, 0, 0, 0};
      const ushort* bp0 = Bt + r * 128 + kg * 8 + ks * 32;
#pragma unroll
      for (int f = 0; f < 8; f++) {
        bf16x8 b = *(const bf16x8*)(bp0 + f * 16 * 128);
        acc[f] = __builtin_amdgcn_mfma_f32_16x16x32_bf16(a, b, acc[f], 0, 0, 0);
      }
    }
  }

  // D layout: lane, reg rr -> row = row0 + kg*4 + rr, col = f*16 + r
  if (MODE == 0) {
    ushort* O = (ushort*)outp;
#pragma unroll
    for (int rr = 0; rr < 4; rr++) {
      int orow = row0 + kg * 4 + rr;
      if (orow < NN) {
#pragma unroll
        for (int f = 0; f < 8; f++) {
          int n = f * 16 + r;
          float h = fmaxf(acc[f][rr] + bias[n], 0.f);
          O[(size_t)orow * DIM + n] = f2b(h);
        }
      }
    }
  } else {
    float* O = (float*)outp;
    float bpv = bp[0], bdv = bd[0];
#pragma unroll
    for (int rr = 0; rr < 4; rr++) {
      float p = 0.f, dv = 0.f;
#pragma unroll
      for (int f = 0; f < 8; f++) {
        int n = f * 16 + r;
        float h = fmaxf(acc[f][rr] + bias[n], 0.f);
        p += h * Wp[n];
        dv += h * Wd[n];
      }
#pragma unroll
      for (int m = 1; m < 16; m <<= 1) {
        p += __shfl_xor(p, m, 64);
        dv += __shfl_xor(dv, m, 64);
      }
      int orow = row0 + kg * 4 + rr;
      if (r == 0 && orow < NN) {
        float preds = p + bpv;
        float diffs = 1.f / (1.f + expf(-(dv + bdv)));
        O[orow] = preds - diffs;
        O[NN + orow] = preds + diffs;
      }
    }
  }
}

extern "C" void kernel_launch(void* const* d_in, const int* in_sizes, int n_in,
                              void* d_out, int out_size, void* d_ws, size_t ws_size,
                              hipStream_t stream) {
  const float* x   = (const float*)d_in[0];
  const void*  ei  = d_in[1];
  const float* W1l = (const float*)d_in[2];
  const float* b1  = (const float*)d_in[3];
  const float* W1r = (const float*)d_in[4];
  const float* W2l = (const float*)d_in[5];
  const float* b2  = (const float*)d_in[6];
  const float* W2r = (const float*)d_in[7];
  const float* Wp  = (const float*)d_in[8];
  const float* bp  = (const float*)d_in[9];
  const float* Wd  = (const float*)d_in[10];
  const float* bd  = (const float*)d_in[11];

  char* ws = (char*)d_ws;
  int* flag   = (int*)(ws + OFF_FLAG);
  int* bsum   = (int*)(ws + OFF_BSUM);
  int* rowptr = (int*)(ws + OFF_ROWPTR);
  int* wcur   = (int*)(ws + OFF_WCUR);
  int* col    = (int*)(ws + OFF_COL);
  ushort* WT  = (ushort*)(ws + OFF_WT);
  ushort* Xb  = (ushort*)(ws + OFF_XB);
  ushort* Hb  = (ushort*)(ws + OFF_HB);
  ushort* Mb  = (ushort*)(ws + OFF_MB);

  hipMemsetAsync(flag, 0, sizeof(int), stream);
  hipMemsetAsync(rowptr, 0, (NN + 1) * sizeof(int), stream);
  k_detect<<<1, 256, 0, stream>>>((const uint*)ei, flag);
  k_hist<<<(NE + 255) / 256, 256, 0, stream>>>(ei, flag, rowptr);
  k_scan_a<<<NB, 1024, 0, stream>>>(rowptr, bsum);
  k_scan_b<<<1, 128, 0, stream>>>(bsum);
  k_scan_c<<<NB, 1024, 0, stream>>>(rowptr, bsum, wcur);
  k_scatter<<<(NE + 255) / 256, 256, 0, stream>>>(ei, flag, wcur, col);

  k_cvt<<<(NN * DIM / 4 + 255) / 256, 256, 0, stream>>>(x, Xb);
  k_cvtw<<<256, 256, 0, stream>>>(W1l, W1r, W2l, W2r, WT);

  // layer 1
  k_agg<<<(NN * 64 + 255) / 256, 256, 0, stream>>>(Xb, rowptr, col, Mb);
  k_mm<0><<<(NN + 63) / 64, 256, 0, stream>>>(Mb, Xb, WT, WT + 16384, b1, Hb,
                                              nullptr, nullptr, nullptr, nullptr);
  // layer 2 + heads
  k_agg<<<(NN * 64 + 255) / 256, 256, 0, stream>>>(Hb, rowptr, col, Mb);
  k_mm<1><<<(NN + 63) / 64, 256, 0, stream>>>(Mb, Hb, WT + 32768, WT + 49152, b2,
                                              d_out, Wp, bp, Wd, bd);
}

// Round 4
// 500.105 us; speedup vs baseline: 1.9344x; 1.0865x over previous
//
#include <hip/hip_runtime.h>
#include <math.h>

constexpr int NN  = 100000;   // nodes
constexpr int NE  = 1600000;  // edges
constexpr int DIM = 128;
constexpr int NB  = (NN + 1 + 1023) / 1024;  // 98 scan blocks
constexpr int NBUCK = (NN + 255) / 256;      // 391 dst-buckets

typedef unsigned short ushort;
typedef unsigned int uint;
typedef __attribute__((ext_vector_type(8))) short bf16x8;
typedef __attribute__((ext_vector_type(4))) float f32x4;

// ---- workspace layout (bytes) ----
constexpr size_t OFF_FLAG   = 0;
constexpr size_t OFF_BSUM   = 512;
constexpr size_t OFF_ROWPTR = 1536;                      // int[NN+1]
constexpr size_t OFF_GCUR   = OFF_ROWPTR + 400128;       // int[NBUCK]
constexpr size_t OFF_COL    = OFF_GCUR   + 2048;         // int[NE]
constexpr size_t OFF_TMP    = OFF_COL    + 6400000;      // uint[NE] packed
constexpr size_t OFF_WT     = OFF_TMP    + 6400000;      // 4 x 128x128 bf16
constexpr size_t OFF_XB     = OFF_WT     + 131072;       // bf16[NN*128]
constexpr size_t OFF_HB     = OFF_XB     + 25600000;     // bf16[NN*128]
constexpr size_t OFF_MB     = OFF_HB     + 25600000;     // bf16[NN*128]
// total ≈ 90.5 MB

__device__ __forceinline__ int eidx(const void* p, int is64, long long i) {
  return is64 ? (int)((const long long*)p)[i] : ((const int*)p)[i];
}

__device__ __forceinline__ ushort f2b(float f) {  // fp32 -> bf16 RNE
  uint u = __float_as_uint(f);
  return (ushort)((u + 0x7FFFu + ((u >> 16) & 1u)) >> 16);
}
__device__ __forceinline__ float blo(uint u) { return __uint_as_float(u << 16); }
__device__ __forceinline__ float bhi(uint u) { return __uint_as_float(u & 0xFFFF0000u); }

__global__ void k_detect(const uint* e, int* flag) {
  uint v = 0;
  for (int i = threadIdx.x; i < 8192; i += blockDim.x) v |= e[2 * i + 1];
  if (v) atomicOr(flag, 1);
}

__global__ void k_hist(const void* e, const int* flag, int* rowptr) {
  int is64 = (*flag == 0);
  int i = blockIdx.x * blockDim.x + threadIdx.x;
  if (i < NE) {
    int dst = eidx(e, is64, (long long)NE + i);
    atomicAdd(&rowptr[dst + 1], 1);
  }
}

// hierarchical scan
__global__ __launch_bounds__(1024) void k_scan_a(int* rowptr, int* bsum) {
  int gid = blockIdx.x * 1024 + threadIdx.x;
  int lane = threadIdx.x & 63;
  int wid = threadIdx.x >> 6;
  int s = (gid < NN + 1) ? rowptr[gid] : 0;
#pragma unroll
  for (int off = 1; off < 64; off <<= 1) {
    int t = __shfl_up(s, off, 64);
    if (lane >= off) s += t;
  }
  __shared__ int wsum[16];
  if (lane == 63) wsum[wid] = s;
  __syncthreads();
  if (wid == 0) {
    int ws = (lane < 16) ? wsum[lane] : 0;
#pragma unroll
    for (int off = 1; off < 16; off <<= 1) {
      int t = __shfl_up(ws, off, 64);
      if (lane >= off) ws += t;
    }
    if (lane < 16) wsum[lane] = ws;
  }
  __syncthreads();
  if (wid > 0) s += wsum[wid - 1];
  if (gid < NN + 1) rowptr[gid] = s;
  if (threadIdx.x == 1023) bsum[blockIdx.x] = s;
}

__global__ void k_scan_b(int* bsum) {
  __shared__ int sh[128];
  int t = threadIdx.x;
  sh[t] = (t < NB) ? bsum[t] : 0;
  __syncthreads();
  for (int off = 1; off < 128; off <<= 1) {
    int v = (t >= off) ? sh[t - off] : 0;
    __syncthreads();
    sh[t] += v;
    __syncthreads();
  }
  if (t < NB) bsum[t] = (t > 0) ? sh[t - 1] : 0;
}

__global__ __launch_bounds__(1024) void k_scan_c(int* rowptr, const int* bsum) {
  int gid = blockIdx.x * 1024 + threadIdx.x;
  if (gid < NN + 1) rowptr[gid] += bsum[blockIdx.x];
}

// seed per-bucket write cursors (tmp shares segment layout with col)
__global__ void k_seed(const int* __restrict__ rowptr, int* __restrict__ gcur) {
  int b = blockIdx.x * blockDim.x + threadIdx.x;
  if (b < NBUCK) gcur[b] = rowptr[min(b << 8, NN)];
}

// LDS multisplit: group edges by dst-bucket into tmp with full-line flushes.
// packed entry = (src << 8) | (dst & 255)
__global__ __launch_bounds__(256) void k_bin(const void* e, const int* flag,
                                             int* gcur, uint* tmp) {
  __shared__ uint buf[NBUCK * 32];
  __shared__ int cnt[NBUCK];
  int is64 = (*flag == 0);
  for (int b = threadIdx.x; b < NBUCK; b += 256) cnt[b] = 0;
  __syncthreads();

  for (int base = blockIdx.x * 256; base < NE; base += gridDim.x * 256) {
    int i = base + threadIdx.x;
    if (i < NE) {
      int src = eidx(e, is64, i);
      int dst = eidx(e, is64, (long long)NE + i);
      int b = dst >> 8;
      uint pack = ((uint)src << 8) | (uint)(dst & 255);
      int c = atomicAdd(&cnt[b], 1);
      if (c < 32) {
        buf[b * 32 + c] = pack;
      } else {  // overflow (pathological skew) - direct fragmented store
        int p = atomicAdd(&gcur[b], 1);
        tmp[p] = pack;
      }
    }
    __syncthreads();
    // flush full 64B lines, one thread per bucket
    for (int b = threadIdx.x; b < NBUCK; b += 256) {
      int c = min(cnt[b], 32);
      if (c >= 16) {
        int gpos = atomicAdd(&gcur[b], 16);
        uint* s = &buf[b * 32];
#pragma unroll
        for (int q = 0; q < 4; q++) {
          uint4 v = {s[q * 4 + 0], s[q * 4 + 1], s[q * 4 + 2], s[q * 4 + 3]};
          *(uint4*)(tmp + gpos + q * 4) = v;
        }
        int rem = c - 16;
        for (int q = 0; q < rem; q++) s[q] = s[16 + q];
        cnt[b] = rem;
      } else {
        cnt[b] = c;
      }
    }
    __syncthreads();
  }
  // final residual flush (partial lines, ~8 entries/bucket/wg)
  for (int b = threadIdx.x; b < NBUCK; b += 256) {
    int c = cnt[b];
    if (c > 0) {
      int gpos = atomicAdd(&gcur[b], c);
      for (int q = 0; q < c; q++) tmp[gpos + q] = buf[b * 32 + q];
    }
  }
}

// one workgroup per bucket: order tmp segment into final CSR col
__global__ __launch_bounds__(256) void k_reorder(const int* __restrict__ rowptr,
                                                 const uint* __restrict__ tmp,
                                                 int* __restrict__ col) {
  __shared__ int lcur[256];
  int b = blockIdx.x;
  int nodeBase = b << 8;
  int segBeg = rowptr[min(nodeBase, NN)];
  int segEnd = rowptr[min(nodeBase + 256, NN)];
  int node = nodeBase + threadIdx.x;
  lcur[threadIdx.x] = rowptr[min(node, NN)];
  __syncthreads();
  for (int j = segBeg + threadIdx.x; j < segEnd; j += 256) {
    uint p = tmp[j];
    int dlocal = p & 255;
    int src = p >> 8;
    int pos = atomicAdd(&lcur[dlocal], 1);
    col[pos] = src;
  }
}

// x fp32 -> bf16
__global__ void k_cvt(const float* __restrict__ x, ushort* __restrict__ xb) {
  int i = blockIdx.x * blockDim.x + threadIdx.x;
  if (i * 4 < NN * DIM) {
    float4 v = ((const float4*)x)[i];
    ushort4 o = {f2b(v.x), f2b(v.y), f2b(v.z), f2b(v.w)};
    ((ushort4*)xb)[i] = o;
  }
}

// 4 weight matrices [k][n] fp32 -> transposed [n][k] bf16
__global__ void k_cvtw(const float* __restrict__ W1l, const float* __restrict__ W1r,
                       const float* __restrict__ W2l, const float* __restrict__ W2r,
                       ushort* __restrict__ WT) {
  int id = blockIdx.x * 256 + threadIdx.x;
  int m = id >> 14, idx = id & 16383;
  int k = idx >> 7, n = idx & 127;
  const float* W = (m == 0) ? W1l : (m == 1) ? W1r : (m == 2) ? W2l : W2r;
  WT[m * 16384 + n * 128 + k] = f2b(W[k * 128 + n]);
}

// One wave per node: mean over in-edges of bf16 features, write bf16 mean.
__global__ void k_agg(const ushort* __restrict__ feat,
                      const int* __restrict__ rowptr,
                      const int* __restrict__ col,
                      ushort* __restrict__ out) {
  int gtid = blockIdx.x * blockDim.x + threadIdx.x;
  int v = gtid >> 6;
  int lane = gtid & 63;
  if (v >= NN) return;
  int beg = rowptr[v], end = rowptr[v + 1];
  const uint* F = (const uint*)feat;
  float ax = 0.f, ay = 0.f;
  int j = beg;
  for (; j + 1 < end; j += 2) {
    uint u0 = F[(size_t)col[j] * 64 + lane];
    uint u1 = F[(size_t)col[j + 1] * 64 + lane];
    ax += blo(u0) + blo(u1);
    ay += bhi(u0) + bhi(u1);
  }
  if (j < end) {
    uint u = F[(size_t)col[j] * 64 + lane];
    ax += blo(u);
    ay += bhi(u);
  }
  float inv = 1.0f / (float)max(end - beg, 1);
  ax *= inv;
  ay *= inv;
  ((uint*)out)[(size_t)v * 64 + lane] = (uint)f2b(ax) | ((uint)f2b(ay) << 16);
}

// MFMA GEMM: C = act(A1@W1 + A2@W2 + bias). Wave = 16 rows x 128 cols.
template <int MODE>
__global__ __launch_bounds__(256) void k_mm(
    const ushort* __restrict__ A1, const ushort* __restrict__ A2,
    const ushort* __restrict__ B1t, const ushort* __restrict__ B2t,
    const float* __restrict__ bias, void* __restrict__ outp,
    const float* __restrict__ Wp, const float* __restrict__ bp,
    const float* __restrict__ Wd, const float* __restrict__ bd) {
  int wid = threadIdx.x >> 6, lane = threadIdx.x & 63;
  int row0 = blockIdx.x * 64 + wid * 16;
  int r = lane & 15, kg = lane >> 4;

  f32x4 acc[8];
#pragma unroll
  for (int f = 0; f < 8; f++) acc[f] = (f32x4){0.f, 0.f, 0.f, 0.f};

  int arow = row0 + r;
  bool aok = arow < NN;
  const ushort* Ar1 = A1 + (size_t)arow * DIM + kg * 8;
  const ushort* Ar2 = A2 + (size_t)arow * DIM + kg * 8;

#pragma unroll
  for (int half = 0; half < 2; half++) {
    const ushort* Ar = half ? Ar2 : Ar1;
    const ushort* Bt = half ? B2t : B1t;
#pragma unroll
    for (int ks = 0; ks < 4; ks++) {
      bf16x8 a = aok ? *(const bf16x8*)(Ar + ks * 32)
                     : (bf16x8){0, 0, 0, 0, 0, 0, 0, 0};
      const ushort* bp0 = Bt + r * 128 + kg * 8 + ks * 32;
#pragma unroll
      for (int f = 0; f < 8; f++) {
        bf16x8 b = *(const bf16x8*)(bp0 + f * 16 * 128);
        acc[f] = __builtin_amdgcn_mfma_f32_16x16x32_bf16(a, b, acc[f], 0, 0, 0);
      }
    }
  }

  if (MODE == 0) {
    ushort* O = (ushort*)outp;
#pragma unroll
    for (int rr = 0; rr < 4; rr++) {
      int orow = row0 + kg * 4 + rr;
      if (orow < NN) {
#pragma unroll
        for (int f = 0; f < 8; f++) {
          int n = f * 16 + r;
          float h = fmaxf(acc[f][rr] + bias[n], 0.f);
          O[(size_t)orow * DIM + n] = f2b(h);
        }
      }
    }
  } else {
    float* O = (float*)outp;
    float bpv = bp[0], bdv = bd[0];
#pragma unroll
    for (int rr = 0; rr < 4; rr++) {
      float p = 0.f, dv = 0.f;
#pragma unroll
      for (int f = 0; f < 8; f++) {
        int n = f * 16 + r;
        float h = fmaxf(acc[f][rr] + bias[n], 0.f);
        p += h * Wp[n];
        dv += h * Wd[n];
      }
#pragma unroll
      for (int m = 1; m < 16; m <<= 1) {
        p += __shfl_xor(p, m, 64);
        dv += __shfl_xor(dv, m, 64);
      }
      int orow = row0 + kg * 4 + rr;
      if (r == 0 && orow < NN) {
        float preds = p + bpv;
        float diffs = 1.f / (1.f + expf(-(dv + bdv)));
        O[orow] = preds - diffs;
        O[NN + orow] = preds + diffs;
      }
    }
  }
}

extern "C" void kernel_launch(void* const* d_in, const int* in_sizes, int n_in,
                              void* d_out, int out_size, void* d_ws, size_t ws_size,
                              hipStream_t stream) {
  const float* x   = (const float*)d_in[0];
  const void*  ei  = d_in[1];
  const float* W1l = (const float*)d_in[2];
  const float* b1  = (const float*)d_in[3];
  const float* W1r = (const float*)d_in[4];
  const float* W2l = (const float*)d_in[5];
  const float* b2  = (const float*)d_in[6];
  const float* W2r = (const float*)d_in[7];
  const float* Wp  = (const float*)d_in[8];
  const float* bp  = (const float*)d_in[9];
  const float* Wd  = (const float*)d_in[10];
  const float* bd  = (const float*)d_in[11];

  char* ws = (char*)d_ws;
  int* flag   = (int*)(ws + OFF_FLAG);
  int* bsum   = (int*)(ws + OFF_BSUM);
  int* rowptr = (int*)(ws + OFF_ROWPTR);
  int* gcur   = (int*)(ws + OFF_GCUR);
  int* col    = (int*)(ws + OFF_COL);
  uint* tmp   = (uint*)(ws + OFF_TMP);
  ushort* WT  = (ushort*)(ws + OFF_WT);
  ushort* Xb  = (ushort*)(ws + OFF_XB);
  ushort* Hb  = (ushort*)(ws + OFF_HB);
  ushort* Mb  = (ushort*)(ws + OFF_MB);

  hipMemsetAsync(flag, 0, sizeof(int), stream);
  hipMemsetAsync(rowptr, 0, (NN + 1) * sizeof(int), stream);
  k_detect<<<1, 256, 0, stream>>>((const uint*)ei, flag);
  k_hist<<<(NE + 255) / 256, 256, 0, stream>>>(ei, flag, rowptr);
  k_scan_a<<<NB, 1024, 0, stream>>>(rowptr, bsum);
  k_scan_b<<<1, 128, 0, stream>>>(bsum);
  k_scan_c<<<NB, 1024, 0, stream>>>(rowptr, bsum);
  k_seed<<<2, 256, 0, stream>>>(rowptr, gcur);
  k_bin<<<128, 256, 0, stream>>>(ei, flag, gcur, tmp);
  k_reorder<<<NBUCK, 256, 0, stream>>>(rowptr, tmp, col);

  k_cvt<<<(NN * DIM / 4 + 255) / 256, 256, 0, stream>>>(x, Xb);
  k_cvtw<<<256, 256, 0, stream>>>(W1l, W1r, W2l, W2r, WT);

  // layer 1
  k_agg<<<(NN * 64 + 255) / 256, 256, 0, stream>>>(Xb, rowptr, col, Mb);
  k_mm<0><<<(NN + 63) / 64, 256, 0, stream>>>(Mb, Xb, WT, WT + 16384, b1, Hb,
                                              nullptr, nullptr, nullptr, nullptr);
  // layer 2 + heads
  k_agg<<<(NN * 64 + 255) / 256, 256, 0, stream>>>(Hb, rowptr, col, Mb);
  k_mm<1><<<(NN + 63) / 64, 256, 0, stream>>>(Mb, Hb, WT + 32768, WT + 49152, b2,
                                              d_out, Wp, bp, Wd, bd);
}